// Round 8
// baseline (223.410 us; speedup 1.0000x reference)
//
#include <hip/hip_runtime.h>

#define NN 50000
#define NE 800000
#define DIMH 128
#define NGRAPH 64
#define NTILES 3125          // 50000 / 16
#define PAIRS 1024           // one wave-pair (=block) per tile stream
#define MLP_ITERS 4          // ceil(3125/1024)
#define NBIN 196             // dst >> 8
#define BCAP 8064            // staging capacity per bin (max load ~4.4K)

typedef __attribute__((ext_vector_type(8))) short bf16x8;
typedef __attribute__((ext_vector_type(4))) float f32x4;

__device__ __forceinline__ unsigned short f2b(float f) {
  unsigned int b = __float_as_uint(f);
  unsigned int r = (b + 0x7FFFu + ((b >> 16) & 1u)) >> 16;  // RNE
  return (unsigned short)r;
}
__device__ __forceinline__ float b2f_lo(unsigned int u) { return __uint_as_float(u << 16); }
__device__ __forceinline__ float b2f_hi(unsigned int u) { return __uint_as_float(u & 0xffff0000u); }
__device__ __forceinline__ unsigned int pk2(float lo, float hi) {
  return (unsigned int)f2b(lo) | ((unsigned int)f2b(hi) << 16);
}
__device__ __forceinline__ void addrow(float* ac, uint4 u0, uint4 u1) {
  ac[0] += b2f_lo(u0.x); ac[1] += b2f_hi(u0.x);
  ac[2] += b2f_lo(u0.y); ac[3] += b2f_hi(u0.y);
  ac[4] += b2f_lo(u0.z); ac[5] += b2f_hi(u0.z);
  ac[6] += b2f_lo(u0.w); ac[7] += b2f_hi(u0.w);
  ac[8] += b2f_lo(u1.x); ac[9] += b2f_hi(u1.x);
  ac[10] += b2f_lo(u1.y); ac[11] += b2f_hi(u1.y);
  ac[12] += b2f_lo(u1.z); ac[13] += b2f_hi(u1.z);
  ac[14] += b2f_lo(u1.w); ac[15] += b2f_hi(u1.w);
}

// ---------------- binned bucket-CSR build ----------------

__global__ __launch_bounds__(256) void bin_scatter_kernel(const int* __restrict__ src,
                                                          const int* __restrict__ dst,
                                                          int* __restrict__ gcnt,
                                                          int2* __restrict__ staging) {
  __shared__ int hist[NBIN];
  __shared__ int base[NBIN];
  int tid = threadIdx.x;
  for (int i = tid; i < NBIN; i += 256) hist[i] = 0;
  __syncthreads();
  int e0 = blockIdx.x * 2048;
  int2 ed[8];
  int bin[8], rank[8];
#pragma unroll
  for (int k = 0; k < 8; ++k) {
    int e = e0 + k * 256 + tid;
    bin[k] = 0; rank[k] = 0; ed[k] = make_int2(0, 0);
    if (e < NE) {
      ed[k].x = src[e]; ed[k].y = dst[e];
      bin[k] = ed[k].y >> 8;
      rank[k] = atomicAdd(&hist[bin[k]], 1);
    }
  }
  __syncthreads();
  for (int i = tid; i < NBIN; i += 256) base[i] = atomicAdd(&gcnt[i], hist[i]);
  __syncthreads();
#pragma unroll
  for (int k = 0; k < 8; ++k) {
    int e = e0 + k * 256 + tid;
    if (e < NE) staging[bin[k] * BCAP + base[bin[k]] + rank[k]] = ed[k];
  }
}

__global__ __launch_bounds__(256) void bin_fill_kernel(const int2* __restrict__ staging,
                                                       const int* __restrict__ gcnt,
                                                       int* __restrict__ bucket,
                                                       int* __restrict__ cnt) {
  __shared__ int h[256];
  int b = blockIdx.x;
  int tid = threadIdx.x;
  h[tid] = 0;
  __syncthreads();
  int n = gcnt[b];
  for (int i = tid; i < n; i += 256) {
    int2 e = staging[b * BCAP + i];
    int local = e.y & 255;
    int r = atomicAdd(&h[local], 1);
    if (r < 64) bucket[(b * 256 + local) * 64 + r] = e.x;
  }
  __syncthreads();
  int node = b * 256 + tid;
  if (node < NN) cnt[node] = h[tid];
}

// ---------------- prep: all 6 weight transposes + out init + gcnt zero ----------------

struct WPtrs { const float* w[6]; const float* b_out; };

__global__ __launch_bounds__(256) void prep_kernel(WPtrs ptrs, unsigned short* __restrict__ wt,
                                                   float* __restrict__ out,
                                                   int* __restrict__ gcnt) {
  int i = blockIdx.x * 256 + threadIdx.x;  // 6*16384 elems, m uniform per block
  int m = i >> 14;
  int idx = i & 16383;
  int c = idx >> 7, k = idx & 127;
  wt[m * 16384 + idx] = f2b(ptrs.w[m][k * DIMH + c]);
  if (i < NGRAPH) out[i] = ptrs.b_out[0];
  if (i < NBIN) gcnt[i] = 0;
}

__global__ void convh_kernel(const float* __restrict__ h, unsigned int* __restrict__ o) {
  int i = blockIdx.x * 256 + threadIdx.x;
  float2 v = ((const float2*)h)[i];
  o[i] = pk2(v.x, v.y);
}

// ---------------- fused layer: gather + MLP + readout, one dispatch ----------------
// Block = one wave-pair (128 threads). H (read) and Y (write) MUST be distinct
// buffers: gather reads arbitrary H rows across tile boundaries, so in-place
// operation races with other blocks' stores (round-7 bug).
__global__ __launch_bounds__(128, 2) void mlp_fused_kernel(
    const unsigned short* __restrict__ H, const int* __restrict__ cnt,
    const int* __restrict__ bucket,
    const unsigned short* __restrict__ W1t, const float* __restrict__ b1,
    const unsigned short* __restrict__ W2t, const float* __restrict__ b2,
    unsigned short* __restrict__ Y,
    const int* __restrict__ gids, const float* __restrict__ wout,
    float* __restrict__ gout) {
  __shared__ unsigned short zt[2][2048];  // 16 rows x 128 cols bf16, dbuf
  __shared__ unsigned short y1[2][2048];
  __shared__ float s_gout[NGRAPH];
  int tid = threadIdx.x;  // 0..127
  if (tid < NGRAPH) s_gout[tid] = 0.f;

  int lane = tid & 63;
  int half = tid >> 6;     // wave id = 64-col half for the GEMMs
  int l15 = lane & 15;
  int g = lane >> 4;
  int r8 = tid >> 3;       // gather: row 0..15
  int s8 = tid & 7;        // gather: feature block 0..7 (feats s8*16..+15)
  int p = blockIdx.x;

  // persistent weight fragments for this wave's 64-col half of W1t and W2t
  bf16x8 fb1[4][4], fb2[4][4];
  const unsigned short* w1b = W1t + (half * 64 + l15) * DIMH + g * 8;
  const unsigned short* w2b = W2t + (half * 64 + l15) * DIMH + g * 8;
#pragma unroll
  for (int n = 0; n < 4; ++n)
#pragma unroll
    for (int kt = 0; kt < 4; ++kt) {
      fb1[n][kt] = *(const bf16x8*)(w1b + n * 16 * DIMH + kt * 32);
      fb2[n][kt] = *(const bf16x8*)(w2b + n * 16 * DIMH + kt * 32);
    }
  float b1v[4], b2v[4], wov[4];
#pragma unroll
  for (int n = 0; n < 4; ++n) {
    int col = half * 64 + n * 16 + l15;
    b1v[n] = b1[col];
    b2v[n] = b2[col];
    wov[n] = wout[col];
  }
  __syncthreads();

#pragma unroll
  for (int i = 0; i < MLP_ITERS; ++i) {
    int rtc = p + i * PAIRS;
    bool active = rtc < NTILES;
    unsigned short* zb = zt[i & 1];
    unsigned short* yb = y1[i & 1];

    if (active) {
      // ---- gather z row r8, features [s8*16, s8*16+16) ----
      int node = rtc * 16 + r8;
      int c = cnt[node];
      if (c > 64) c = 64;
      const uint4* hb = (const uint4*)H;
      float ac[16];
      {
        uint4 v0 = hb[node * 16 + s8 * 2];
        uint4 v1 = hb[node * 16 + s8 * 2 + 1];
        ac[0] = b2f_lo(v0.x); ac[1] = b2f_hi(v0.x);
        ac[2] = b2f_lo(v0.y); ac[3] = b2f_hi(v0.y);
        ac[4] = b2f_lo(v0.z); ac[5] = b2f_hi(v0.z);
        ac[6] = b2f_lo(v0.w); ac[7] = b2f_hi(v0.w);
        ac[8] = b2f_lo(v1.x); ac[9] = b2f_hi(v1.x);
        ac[10] = b2f_lo(v1.y); ac[11] = b2f_hi(v1.y);
        ac[12] = b2f_lo(v1.z); ac[13] = b2f_hi(v1.z);
        ac[14] = b2f_lo(v1.w); ac[15] = b2f_hi(v1.w);
      }
      const int* bk = bucket + node * 64;
      int j = 0;
      for (; j + 4 <= c; j += 4) {
        int n0 = bk[j], n1 = bk[j + 1], n2 = bk[j + 2], n3 = bk[j + 3];
        uint4 a0 = hb[n0 * 16 + s8 * 2], a1 = hb[n0 * 16 + s8 * 2 + 1];
        uint4 c0 = hb[n1 * 16 + s8 * 2], c1 = hb[n1 * 16 + s8 * 2 + 1];
        uint4 d0 = hb[n2 * 16 + s8 * 2], d1 = hb[n2 * 16 + s8 * 2 + 1];
        uint4 e0 = hb[n3 * 16 + s8 * 2], e1 = hb[n3 * 16 + s8 * 2 + 1];
        addrow(ac, a0, a1);
        addrow(ac, c0, c1);
        addrow(ac, d0, d1);
        addrow(ac, e0, e1);
      }
      for (; j < c; ++j) {
        int nb = bk[j];
        uint4 u0 = hb[nb * 16 + s8 * 2], u1 = hb[nb * 16 + s8 * 2 + 1];
        addrow(ac, u0, u1);
      }
      uint4 o0, o1;
      o0.x = pk2(ac[0], ac[1]);  o0.y = pk2(ac[2], ac[3]);
      o0.z = pk2(ac[4], ac[5]);  o0.w = pk2(ac[6], ac[7]);
      o1.x = pk2(ac[8], ac[9]);  o1.y = pk2(ac[10], ac[11]);
      o1.z = pk2(ac[12], ac[13]); o1.w = pk2(ac[14], ac[15]);
      int byte0 = (r8 * 256 + s8 * 32) ^ (r8 << 4);
      *(uint4*)((char*)zb + byte0) = o0;
      *(uint4*)((char*)zb + (byte0 ^ 16)) = o1;
    }

    __syncthreads();  // z tile complete

    if (active) {
      // ---- GEMM1: A from z LDS ----
      bf16x8 a[4];
#pragma unroll
      for (int kt = 0; kt < 4; ++kt)
        a[kt] = *(const bf16x8*)((const char*)zb +
                                 ((l15 * 256 + kt * 64 + g * 16) ^ (l15 << 4)));
#pragma unroll
      for (int n = 0; n < 4; ++n) {
        f32x4 acc = (f32x4){0.f, 0.f, 0.f, 0.f};
#pragma unroll
        for (int kt = 0; kt < 4; ++kt)
          acc = __builtin_amdgcn_mfma_f32_16x16x32_bf16(a[kt], fb1[n][kt], acc, 0, 0, 0);
        int col2 = (half * 64 + n * 16 + l15) * 2;
#pragma unroll
        for (int r = 0; r < 4; ++r) {
          float f = fmaxf(acc[r] + b1v[n], 0.f);
          int row = 4 * g + r;
          yb[((row * 256 + col2) ^ (row << 4)) >> 1] = f2b(f);
        }
      }
    }

    __syncthreads();  // y1 tile complete

    if (active) {
      // ---- GEMM2 + store + readout ----
      bf16x8 a2[4];
#pragma unroll
      for (int kt = 0; kt < 4; ++kt)
        a2[kt] = *(const bf16x8*)((const char*)yb +
                                  ((l15 * 256 + kt * 64 + g * 16) ^ (l15 << 4)));
      float pr[4] = {0.f, 0.f, 0.f, 0.f};
#pragma unroll
      for (int n = 0; n < 4; ++n) {
        f32x4 acc = (f32x4){0.f, 0.f, 0.f, 0.f};
#pragma unroll
        for (int kt = 0; kt < 4; ++kt)
          acc = __builtin_amdgcn_mfma_f32_16x16x32_bf16(a2[kt], fb2[n][kt], acc, 0, 0, 0);
        int col = half * 64 + n * 16 + l15;
#pragma unroll
        for (int r = 0; r < 4; ++r) {
          float f = acc[r] + b2v[n];
          if (Y) Y[(rtc * 16 + 4 * g + r) * DIMH + col] = f2b(f);
          pr[r] += f * wov[n];
        }
      }
#pragma unroll
      for (int r = 0; r < 4; ++r) {
#pragma unroll
        for (int off = 1; off < 16; off <<= 1) pr[r] += __shfl_xor(pr[r], off, 64);
      }
      if (l15 == 0) {
#pragma unroll
        for (int r = 0; r < 4; ++r)
          atomicAdd(&s_gout[gids[rtc * 16 + 4 * g + r]], pr[r]);
      }
    }
  }

  __syncthreads();
  if (tid < NGRAPH) {
    float v = s_gout[tid];
    if (v != 0.f) atomicAdd(&gout[tid], v);
  }
}

// ---------------- launch ----------------

extern "C" void kernel_launch(void* const* d_in, const int* in_sizes, int n_in,
                              void* d_out, int out_size, void* d_ws, size_t ws_size,
                              hipStream_t stream) {
  const float* h = (const float*)d_in[0];
  const int* src = (const int*)d_in[1];
  const int* dst = (const int*)d_in[2];
  const int* gids = (const int*)d_in[3];
  const float* w_out = (const float*)d_in[16];
  const float* b_out = (const float*)d_in[17];
  float* out = (float*)d_out;

  char* base = (char*)d_ws;
  unsigned short* buf0 = (unsigned short*)(base);             // 12,800,000 B (layer io ping)
  unsigned short* buf1 = (unsigned short*)(base + 12800000);  // 12,800,000 B (layer io pong)
  int2* staging = (int2*)(base + 25600000);                   // 12,644,352 B
  int* bucket = (int*)(base + 38400000);                      // 12,800,000 B
  int* cnt = (int*)(base + 51200000);                         // 200,000 B
  int* gcnt = (int*)(base + 51400064);                        // 784 B
  unsigned short* wt = (unsigned short*)(base + 51401024);    // 6 x 32,768 B

  WPtrs ptrs;
  for (int l = 0; l < 3; ++l) {
    ptrs.w[2 * l] = (const float*)d_in[4 + l * 4];
    ptrs.w[2 * l + 1] = (const float*)d_in[6 + l * 4];
  }
  ptrs.b_out = b_out;

  // prep (wt transpose-convert, out init, gcnt zero) -> CSR build -> h convert
  prep_kernel<<<384, 256, 0, stream>>>(ptrs, wt, out, gcnt);
  bin_scatter_kernel<<<(NE + 2047) / 2048, 256, 0, stream>>>(src, dst, gcnt, staging);
  bin_fill_kernel<<<NBIN, 256, 0, stream>>>(staging, gcnt, bucket, cnt);
  convh_kernel<<<(NN * 64) / 256, 256, 0, stream>>>(h, (unsigned int*)buf0);

  for (int l = 0; l < 3; ++l) {
    const float* b1 = (const float*)d_in[5 + l * 4];
    const float* b2 = (const float*)d_in[7 + l * 4];
    const unsigned short* Hl = (l & 1) ? buf1 : buf0;   // read
    unsigned short* Yl = (l & 1) ? buf0 : buf1;         // write (distinct!)
    mlp_fused_kernel<<<PAIRS, 128, 0, stream>>>(
        Hl, cnt, bucket,
        wt + (2 * l) * 16384, b1, wt + (2 * l + 1) * 16384, b2,
        (l == 2) ? nullptr : Yl,
        gids, w_out + l * DIMH, out);
  }
}